// Round 3
// baseline (390.462 us; speedup 1.0000x reference)
//
#include <hip/hip_runtime.h>
#include <hip/hip_bf16.h>
#include <math.h>

// IDSCT2: out[b,u,v] = sum_{p,q} x[b,p,q] * S[u,p] * C[v,q]
//   S[u,p] = sin(pi*(2u+1)*p/(2M)), C[v,q] = cos(pi*(2v+1)*q/(2N))
// Two bf16-MFMA NT GEMMs per batch:
//   pass1: tT[b][v][p] = sum_q C[v][q] * xb[b][p][q]     (A=C, B=x[b])
//   pass2: out[b][u][v] = sum_p S[u][p] * tT[b][v][p]    (A=S, B=tT[b])
// R3: FRAG-MAJOR LDS staging. global_load_lds writes lane l -> base+l*16
// (hardware rule). We permute the *global* source so lane l fetches exactly
// fragment-lane l's bytes: each 16-row x 32-col fragment tile lands as a
// contiguous 1 KiB LDS block. Fragment ds_read_b128 then reads base+lane*16
// -- linear, bank-conflict-free by construction (same pattern as the write).

#define BM 128
#define BN 128
#define BK 32

typedef __bf16 bf16x8 __attribute__((ext_vector_type(8)));
typedef __bf16 bf16x4 __attribute__((ext_vector_type(4)));
typedef float floatx4 __attribute__((ext_vector_type(4)));

__device__ __forceinline__ void async_ld16(const void* g, void* l) {
    __builtin_amdgcn_global_load_lds(
        (__attribute__((address_space(1))) void*)(g),
        (__attribute__((address_space(3))) void*)(l), 16, 0, 0);
}

// Cb[v*2048+q] = cos(pi*(2v+1)*q/4096), Sb[u*2048+p] = sin(same phase).
// Integer phase mod 8192 keeps the fp32 trig arg < 2*pi (exact in int32).
__global__ void basis_kernel(__bf16* __restrict__ Cb, __bf16* __restrict__ Sb) {
    int idx = blockIdx.x * 256 + threadIdx.x;
    int v = idx >> 11;
    int q = idx & 2047;
    int phase = ((2 * v + 1) * q) & 8191;
    float ang = (float)phase * 7.669903939428206e-04f;  // pi/4096
    Cb[idx] = (__bf16)__cosf(ang);
    Sb[idx] = (__bf16)__sinf(ang);
}

// fp32 -> bf16, 4 elements/thread
__global__ void cvt_kernel(const float4* __restrict__ x, bf16x4* __restrict__ xb) {
    int i = blockIdx.x * 256 + threadIdx.x;
    float4 v = x[i];
    bf16x4 o;
    o[0] = (__bf16)v.x;
    o[1] = (__bf16)v.y;
    o[2] = (__bf16)v.z;
    o[3] = (__bf16)v.w;
    xb[i] = o;
}

// NT GEMM: D[i*Ndim+j] = sum_k A[i*K+k] * B[j*K+k], per blockIdx.z batch.
// 128x128 tile, BK=32, 256 threads = 4 waves (2x2, each wave 64x64 via 4x4
// mfma_f32_16x16x32_bf16). Double-buffered LDS; stage(k+1) issued after the
// barrier so vmem latency overlaps compute(k).
//
// LDS layout (per matrix, per buffer): 8 fragment tiles of 512 elements.
// Frag tile f holds rows [f*16, f*16+16) x all 32 k; within it, lane l owns
// the 8 bf16 at (row = f*16 + (l&15), k = (l>>4)*8 .. +8) at offset l*16 B.
// This matches the MFMA A/B operand layout (verified end-to-end in R1):
//   A-frag: lane holds A[m=lane&15][k=(lane>>4)*8 + j], j=0..7.
template <typename OutT>
__global__ void __launch_bounds__(256) gemm_nt(
    const __bf16* __restrict__ A, const __bf16* __restrict__ B,
    OutT* __restrict__ D, int Ndim, int K,
    long batchA, long batchB, long batchD) {
    __shared__ __bf16 As[2][BM * BK];  // 2 x 8 KiB
    __shared__ __bf16 Bs[2][BN * BK];  // 2 x 8 KiB

    const int tid = threadIdx.x;
    const int lane = tid & 63;
    const int wave = tid >> 6;
    const int wr = wave >> 1;
    const int wc = wave & 1;

    A += batchA * blockIdx.z;
    B += batchB * blockIdx.z;
    D += batchD * blockIdx.z;

    const int row0 = blockIdx.y * BM;
    const int col0 = blockIdx.x * BN;

    // Staging (frag-major): wave w stages frag tiles {2w, 2w+1} of A and B.
    // Lane l fetches global (row = tile_row0 + f*16 + (l&15), k chunk l>>4).
    // Wave's global footprint: 16 rows x 64 B contiguous each (lanes
    // {m,m+16,m+32,m+48} cover row m's four 16 B chunks) -- same coalescing
    // as row-major staging, different lane permutation.
    const int frow = (lane & 15);
    const int fchunk = (lane >> 4) * 8;
    const int srow = wave * 32 + frow;  // frag tile 2w row
    const __bf16* a_src0 = A + (size_t)(row0 + srow) * K + fchunk;
    const __bf16* a_src1 = a_src0 + (size_t)16 * K;   // frag tile 2w+1
    const __bf16* b_src0 = B + (size_t)(col0 + srow) * K + fchunk;
    const __bf16* b_src1 = b_src0 + (size_t)16 * K;
    const int ldst0 = wave * 1024;        // frag tile 2w  -> elements
    const int ldst1 = wave * 1024 + 512;  // frag tile 2w+1

    const int lane16 = lane * 8;  // element offset of this lane's 16 B

    floatx4 acc[4][4] = {};

    const int nIter = K / BK;

    // Prologue: stage k-tile 0 into buffer 0.
    async_ld16(a_src0, &As[0][ldst0]);
    async_ld16(a_src1, &As[0][ldst1]);
    async_ld16(b_src0, &Bs[0][ldst0]);
    async_ld16(b_src1, &Bs[0][ldst1]);

    for (int it = 0; it < nIter; ++it) {
        const int cur = it & 1;
        // Barrier: (a) compiler's vmcnt(0) guarantees buf[cur] staged;
        // (b) all waves are done reading buf[cur^1], safe to restage below.
        __syncthreads();

        if (it + 1 < nIter) {
            const int nxt = cur ^ 1;
            const size_t k1 = (size_t)(it + 1) * BK;
            async_ld16(a_src0 + k1, &As[nxt][ldst0]);
            async_ld16(a_src1 + k1, &As[nxt][ldst1]);
            async_ld16(b_src0 + k1, &Bs[nxt][ldst0]);
            async_ld16(b_src1 + k1, &Bs[nxt][ldst1]);
        }

        // Fragment reads: frag tile index = wave_row*4 + t; address is
        // uniform base + lane*16 -- conflict-free linear.
        bf16x8 af[4], bfr[4];
#pragma unroll
        for (int t = 0; t < 4; ++t) {
            af[t]  = *(const bf16x8*)&As[cur][(wr * 4 + t) * 512 + lane16];
            bfr[t] = *(const bf16x8*)&Bs[cur][(wc * 4 + t) * 512 + lane16];
        }
#pragma unroll
        for (int i = 0; i < 4; ++i)
#pragma unroll
            for (int j = 0; j < 4; ++j)
                acc[i][j] = __builtin_amdgcn_mfma_f32_16x16x32_bf16(
                    af[i], bfr[j], acc[i][j], 0, 0, 0);
    }

    // Epilogue: C/D layout col=lane&15, row=(lane>>4)*4+reg (verified).
    const int ecol = lane & 15;
    const int erow = (lane >> 4) * 4;
#pragma unroll
    for (int i = 0; i < 4; ++i)
#pragma unroll
        for (int j = 0; j < 4; ++j)
#pragma unroll
            for (int r = 0; r < 4; ++r) {
                int gi = row0 + wr * 64 + i * 16 + erow + r;
                int gj = col0 + wc * 64 + j * 16 + ecol;
                D[(size_t)gi * Ndim + gj] = (OutT)acc[i][j][r];
            }
}

extern "C" void kernel_launch(void* const* d_in, const int* in_sizes, int n_in,
                              void* d_out, int out_size, void* d_ws, size_t ws_size,
                              hipStream_t stream) {
    const float* x = (const float*)d_in[0];
    float* out = (float*)d_out;

    const int MN = 2048;
    const size_t mat = (size_t)MN * MN;  // 4M elems
    const size_t bmat = 4 * mat;         // 16M elems (B=4)

    // Workspace layout (80 MiB total):
    __bf16* Cb = (__bf16*)d_ws;   //  8 MiB
    __bf16* Sb = Cb + mat;        //  8 MiB
    __bf16* xb = Sb + mat;        // 32 MiB
    __bf16* tT = xb + bmat;       // 32 MiB

    basis_kernel<<<mat / 256, 256, 0, stream>>>(Cb, Sb);
    cvt_kernel<<<bmat / 4 / 256, 256, 0, stream>>>((const float4*)x, (bf16x4*)xb);

    dim3 grid(MN / BN, MN / BM, 4);
    // pass1: tT[b][v][p] = sum_q C[v][q] * xb[b][p][q]
    gemm_nt<__bf16><<<grid, 256, 0, stream>>>(Cb, xb, tT, MN, MN,
                                              0L, (long)mat, (long)mat);
    // pass2: out[b][u][v] = sum_p S[u][p] * tT[b][v][p]
    gemm_nt<float><<<grid, 256, 0, stream>>>(Sb, tT, out, MN, MN,
                                             0L, (long)mat, (long)mat);
}

// Round 4
// 271.179 us; speedup vs baseline: 1.4399x; 1.4399x over previous
//
#include <hip/hip_runtime.h>
#include <hip/hip_bf16.h>
#include <math.h>

// IDSCT2: out[b,u,v] = sum_{p,q} x[b,p,q] * S[u,p] * C[v,q]
// Two bf16-MFMA NT GEMMs per batch:
//   pass1: tT[b][v][p] = sum_q C[v][q] * xb[b][p][q]     (A=C, B=x[b])
//   pass2: out[b][u][v] = sum_p S[u][p] * tT[b][v][p]    (A=S, B=tT[b])
// R4: revert R3's frag-major staging (broke global coalescing: 64 singleton
// 16B transactions/instr vs 16x64B). Back to R2 row-major staging. Raise
// arithmetic intensity instead: 64x128 wave tile (acc 4x8), 128x256 block,
// 4 waves. LDS reads/MFMA drop 2.0 -> 2.67 MFMA per b128; per-CU LDS demand
// ~2000 -> ~1400 cyc/iter. Double-buffered, stage(k+1) issued post-barrier.

#define BM 128   // block rows (A / output rows)
#define BN 256   // block cols (B / output cols)
#define BK 32

typedef __bf16 bf16x8 __attribute__((ext_vector_type(8)));
typedef __bf16 bf16x4 __attribute__((ext_vector_type(4)));
typedef float floatx4 __attribute__((ext_vector_type(4)));

__device__ __forceinline__ void async_ld16(const void* g, void* l) {
    __builtin_amdgcn_global_load_lds(
        (__attribute__((address_space(1))) void*)(g),
        (__attribute__((address_space(3))) void*)(l), 16, 0, 0);
}

// Cb[v*2048+q] = cos(pi*(2v+1)*q/4096), Sb[u*2048+p] = sin(same phase).
// Integer phase mod 8192 keeps the fp32 trig arg < 2*pi (exact in int32).
__global__ void basis_kernel(__bf16* __restrict__ Cb, __bf16* __restrict__ Sb) {
    int idx = blockIdx.x * 256 + threadIdx.x;
    int v = idx >> 11;
    int q = idx & 2047;
    int phase = ((2 * v + 1) * q) & 8191;
    float ang = (float)phase * 7.669903939428206e-04f;  // pi/4096
    Cb[idx] = (__bf16)__cosf(ang);
    Sb[idx] = (__bf16)__sinf(ang);
}

// fp32 -> bf16, 4 elements/thread
__global__ void cvt_kernel(const float4* __restrict__ x, bf16x4* __restrict__ xb) {
    int i = blockIdx.x * 256 + threadIdx.x;
    float4 v = x[i];
    bf16x4 o;
    o[0] = (__bf16)v.x;
    o[1] = (__bf16)v.y;
    o[2] = (__bf16)v.z;
    o[3] = (__bf16)v.w;
    xb[i] = o;
}

// NT GEMM: D[i*Ndim+j] = sum_k A[i*K+k] * B[j*K+k], per blockIdx.z batch.
// 128x256 tile, BK=32, 256 threads = 4 waves (2x2 wave grid, each wave
// 64 rows x 128 cols via 4x8 mfma_f32_16x16x32_bf16 tiles).
// Staging (R2 row-major): lane l -> slot row l>>2, 16B chunk (l&3)*16B --
// 4 consecutive lanes cover one contiguous 64B row segment (good VMEM
// coalescing); LDS dst = wave-uniform base + lane*16 -> [row][BK] row-major.
template <typename OutT>
__global__ void __launch_bounds__(256, 2) gemm_nt(
    const __bf16* __restrict__ A, const __bf16* __restrict__ B,
    OutT* __restrict__ D, int Ndim, int K,
    long batchA, long batchB, long batchD) {
    __shared__ __bf16 As[2][BM * BK];  // 2 x 8 KiB
    __shared__ __bf16 Bs[2][BN * BK];  // 2 x 16 KiB

    const int tid = threadIdx.x;
    const int lane = tid & 63;
    const int wave = tid >> 6;
    const int wr = wave >> 1;  // 0..1: row offset wr*64
    const int wc = wave & 1;   // 0..1: col offset wc*128

    A += batchA * blockIdx.z;
    B += batchB * blockIdx.z;
    D += batchD * blockIdx.z;

    const int row0 = blockIdx.y * BM;
    const int col0 = blockIdx.x * BN;

    // Staging assignment: wave w stages A slots {2w,2w+1} (16 rows each) and
    // B slots {4w..4w+3}. Lane l -> row +l/4, chunk (l&3)*8 elems.
    const int chunk = (lane & 3) * 8;
    const int lrow = lane >> 2;
    const __bf16* a_src0 = A + (size_t)(row0 + wave * 32 + lrow) * K + chunk;
    const __bf16* a_src1 = a_src0 + (size_t)16 * K;
    const __bf16* b_src0 = B + (size_t)(col0 + wave * 64 + lrow) * K + chunk;
    const __bf16* b_src1 = b_src0 + (size_t)16 * K;
    const __bf16* b_src2 = b_src0 + (size_t)32 * K;
    const __bf16* b_src3 = b_src0 + (size_t)48 * K;
    const int aDst = wave * 1024;  // elems: slot 2w base (2 slots x 512)
    const int bDst = wave * 2048;  // elems: slot 4w base (4 slots x 512)

    // MFMA fragment addressing (verified R1):
    //   A-frag: lane holds A[m=lane&15][k=(lane>>4)*8 + j], j=0..7
    //   B-frag: lane holds B[n=lane&15][k=(lane>>4)*8 + j]  (NT: Bs rows = n)
    const int mrow = lane & 15;
    const int q8 = (lane >> 4) * 8;

    floatx4 acc[4][8] = {};

    const int nIter = K / BK;

    // Prologue: stage k-tile 0 into buffer 0.
    async_ld16(a_src0, &As[0][aDst]);
    async_ld16(a_src1, &As[0][aDst + 512]);
    async_ld16(b_src0, &Bs[0][bDst]);
    async_ld16(b_src1, &Bs[0][bDst + 512]);
    async_ld16(b_src2, &Bs[0][bDst + 1024]);
    async_ld16(b_src3, &Bs[0][bDst + 1536]);

    for (int it = 0; it < nIter; ++it) {
        const int cur = it & 1;
        // Barrier: (a) compiler's vmcnt(0) guarantees buf[cur] staged;
        // (b) all waves done reading buf[cur^1], safe to restage below.
        __syncthreads();

        if (it + 1 < nIter) {
            const int nxt = cur ^ 1;
            const size_t k1 = (size_t)(it + 1) * BK;
            async_ld16(a_src0 + k1, &As[nxt][aDst]);
            async_ld16(a_src1 + k1, &As[nxt][aDst + 512]);
            async_ld16(b_src0 + k1, &Bs[nxt][bDst]);
            async_ld16(b_src1 + k1, &Bs[nxt][bDst + 512]);
            async_ld16(b_src2 + k1, &Bs[nxt][bDst + 1024]);
            async_ld16(b_src3 + k1, &Bs[nxt][bDst + 1536]);
        }

        bf16x8 af[4], bfr[8];
#pragma unroll
        for (int t = 0; t < 4; ++t)
            af[t] = *(const bf16x8*)&As[cur][(wr * 64 + t * 16 + mrow) * BK + q8];
#pragma unroll
        for (int t = 0; t < 8; ++t)
            bfr[t] = *(const bf16x8*)&Bs[cur][(wc * 128 + t * 16 + mrow) * BK + q8];
#pragma unroll
        for (int i = 0; i < 4; ++i)
#pragma unroll
            for (int j = 0; j < 8; ++j)
                acc[i][j] = __builtin_amdgcn_mfma_f32_16x16x32_bf16(
                    af[i], bfr[j], acc[i][j], 0, 0, 0);
    }

    // Epilogue: C/D layout col=lane&15, row=(lane>>4)*4+reg (verified).
    const int ecol = lane & 15;
    const int erow = (lane >> 4) * 4;
#pragma unroll
    for (int i = 0; i < 4; ++i)
#pragma unroll
        for (int j = 0; j < 8; ++j)
#pragma unroll
            for (int r = 0; r < 4; ++r) {
                int gi = row0 + wr * 64 + i * 16 + erow + r;
                int gj = col0 + wc * 128 + j * 16 + ecol;
                D[(size_t)gi * Ndim + gj] = (OutT)acc[i][j][r];
            }
}

extern "C" void kernel_launch(void* const* d_in, const int* in_sizes, int n_in,
                              void* d_out, int out_size, void* d_ws, size_t ws_size,
                              hipStream_t stream) {
    const float* x = (const float*)d_in[0];
    float* out = (float*)d_out;

    const int MN = 2048;
    const size_t mat = (size_t)MN * MN;  // 4M elems
    const size_t bmat = 4 * mat;         // 16M elems (B=4)

    // Workspace layout (80 MiB total):
    __bf16* Cb = (__bf16*)d_ws;   //  8 MiB
    __bf16* Sb = Cb + mat;        //  8 MiB
    __bf16* xb = Sb + mat;        // 32 MiB
    __bf16* tT = xb + bmat;       // 32 MiB

    basis_kernel<<<mat / 256, 256, 0, stream>>>(Cb, Sb);
    cvt_kernel<<<bmat / 4 / 256, 256, 0, stream>>>((const float4*)x, (bf16x4*)xb);

    dim3 grid(MN / BN, MN / BM, 4);  // (8, 16, 4) = 512 blocks
    // pass1: tT[b][v][p] = sum_q C[v][q] * xb[b][p][q]
    gemm_nt<__bf16><<<grid, 256, 0, stream>>>(Cb, xb, tT, MN, MN,
                                              0L, (long)mat, (long)mat);
    // pass2: out[b][u][v] = sum_p S[u][p] * tT[b][v][p]
    gemm_nt<float><<<grid, 256, 0, stream>>>(Sb, tT, out, MN, MN,
                                             0L, (long)mat, (long)mat);
}

// Round 5
// 260.102 us; speedup vs baseline: 1.5012x; 1.0426x over previous
//
#include <hip/hip_runtime.h>
#include <hip/hip_bf16.h>
#include <math.h>

// IDSCT2: out[b,u,v] = sum_{p,q} x[b,p,q] * S[u,p] * C[v,q]
// Two bf16-MFMA NT GEMMs per batch:
//   pass1: tT[b][v][p] = sum_q C[v][q] * xb[b][p][q]     (A=C, B=x[b])
//   pass2: out[b][u][v] = sum_p S[u][p] * tT[b][v][p]    (A=S, B=tT[b])
// R5: (a) occupancy 2x: 512 threads = 8 waves of 64x64 (wave grid 2x4),
// 128x256 block -> 16 waves/CU (4/SIMD) vs R4's 8. (b) XOR chunk swizzle:
// LDS chunk slot q of row r holds global chunk q^s(r), s(r)=((r&15)>>1)&3.
// Staging lane permutation stays within each 64B line (coalescing intact);
// fragment reads then spread over all 8 bank groups at 2-way (free, m136).

#define BM 128   // block rows (A / output rows)
#define BN 256   // block cols (B / output cols)
#define BK 32

typedef __bf16 bf16x8 __attribute__((ext_vector_type(8)));
typedef __bf16 bf16x4 __attribute__((ext_vector_type(4)));
typedef float floatx4 __attribute__((ext_vector_type(4)));

__device__ __forceinline__ void async_ld16(const void* g, void* l) {
    __builtin_amdgcn_global_load_lds(
        (__attribute__((address_space(1))) void*)(g),
        (__attribute__((address_space(3))) void*)(l), 16, 0, 0);
}

// Cb[v*2048+q] = cos(pi*(2v+1)*q/4096), Sb[u*2048+p] = sin(same phase).
// Integer phase mod 8192 keeps the fp32 trig arg < 2*pi (exact in int32).
__global__ void basis_kernel(__bf16* __restrict__ Cb, __bf16* __restrict__ Sb) {
    int idx = blockIdx.x * 256 + threadIdx.x;
    int v = idx >> 11;
    int q = idx & 2047;
    int phase = ((2 * v + 1) * q) & 8191;
    float ang = (float)phase * 7.669903939428206e-04f;  // pi/4096
    Cb[idx] = (__bf16)__cosf(ang);
    Sb[idx] = (__bf16)__sinf(ang);
}

// fp32 -> bf16, 4 elements/thread
__global__ void cvt_kernel(const float4* __restrict__ x, bf16x4* __restrict__ xb) {
    int i = blockIdx.x * 256 + threadIdx.x;
    float4 v = x[i];
    bf16x4 o;
    o[0] = (__bf16)v.x;
    o[1] = (__bf16)v.y;
    o[2] = (__bf16)v.z;
    o[3] = (__bf16)v.w;
    xb[i] = o;
}

// NT GEMM: D[i*Ndim+j] = sum_k A[i*K+k] * B[j*K+k], per blockIdx.z batch.
// 128x256 tile, BK=32, 512 threads = 8 waves (2x4 wave grid, each wave
// 64x64 via 4x4 mfma_f32_16x16x32_bf16). Double-buffered LDS; stage(k+1)
// issued after the barrier so vmem latency overlaps compute(k).
//
// LDS layout: row-major [row][BK] in 16-row "slots" (one glds instr = one
// slot = 1 KiB), with the chunk swizzle described above. Staging: lane l ->
// slot row l>>2, chunk slot l&3, fetching global chunk (l&3)^s(row).
template <typename OutT>
__global__ void __launch_bounds__(512, 4) gemm_nt(
    const __bf16* __restrict__ A, const __bf16* __restrict__ B,
    OutT* __restrict__ D, int Ndim, int K,
    long batchA, long batchB, long batchD) {
    __shared__ __bf16 As[2][BM * BK];  // 2 x 8 KiB
    __shared__ __bf16 Bs[2][BN * BK];  // 2 x 16 KiB

    const int tid = threadIdx.x;
    const int lane = tid & 63;
    const int wave = tid >> 6;   // 0..7
    const int wr = wave >> 2;    // 0..1: row offset wr*64
    const int wc = wave & 3;     // 0..3: col offset wc*64

    A += batchA * blockIdx.z;
    B += batchB * blockIdx.z;
    D += batchD * blockIdx.z;

    const int row0 = blockIdx.y * BM;
    const int col0 = blockIdx.x * BN;

    // Staging: wave w stages A slot w (rows 16w..16w+16) and B slots
    // {2w, 2w+1} (rows 32w..32w+32). Lane l -> row +l/4, global chunk
    // ((l&3) ^ s(lrow)) * 8 elems; s(r) = ((r&15)>>1)&3.
    const int lrow = lane >> 2;
    const int sst = (lrow >> 1) & 3;
    const int goff = (((lane & 3) ^ sst) * 8);
    const __bf16* a_src = A + (size_t)(row0 + wave * 16 + lrow) * K + goff;
    const __bf16* b_src0 = B + (size_t)(col0 + wave * 32 + lrow) * K + goff;
    const __bf16* b_src1 = b_src0 + (size_t)16 * K;
    const int aDst = wave * 512;       // elems: A slot w
    const int bDst = wave * 1024;      // elems: B slot 2w (2 slots x 512)

    // MFMA fragment addressing (verified R1):
    //   A-frag: lane holds A[m=lane&15][k=(lane>>4)*8 + j], j=0..7
    //   B-frag: lane holds B[n=lane&15][k=(lane>>4)*8 + j]  (NT: Bs rows = n)
    // Swizzle on read: chunk (lane>>4) lives at slot (lane>>4)^s(mrow).
    const int mrow = lane & 15;
    const int swr = (mrow >> 1) & 3;
    const int qoff = (((lane >> 4) ^ swr) * 8);

    floatx4 acc[4][4] = {};

    const int nIter = K / BK;

    // Prologue: stage k-tile 0 into buffer 0.
    async_ld16(a_src, &As[0][aDst]);
    async_ld16(b_src0, &Bs[0][bDst]);
    async_ld16(b_src1, &Bs[0][bDst + 512]);

    for (int it = 0; it < nIter; ++it) {
        const int cur = it & 1;
        // Barrier: (a) compiler's vmcnt(0) guarantees buf[cur] staged;
        // (b) all waves done reading buf[cur^1], safe to restage below.
        __syncthreads();

        if (it + 1 < nIter) {
            const int nxt = cur ^ 1;
            const size_t k1 = (size_t)(it + 1) * BK;
            async_ld16(a_src + k1, &As[nxt][aDst]);
            async_ld16(b_src0 + k1, &Bs[nxt][bDst]);
            async_ld16(b_src1 + k1, &Bs[nxt][bDst + 512]);
        }

        bf16x8 af[4], bfr[4];
#pragma unroll
        for (int t = 0; t < 4; ++t)
            af[t] = *(const bf16x8*)&As[cur][(wr * 64 + t * 16 + mrow) * BK + qoff];
#pragma unroll
        for (int t = 0; t < 4; ++t)
            bfr[t] = *(const bf16x8*)&Bs[cur][(wc * 64 + t * 16 + mrow) * BK + qoff];
#pragma unroll
        for (int i = 0; i < 4; ++i)
#pragma unroll
            for (int j = 0; j < 4; ++j)
                acc[i][j] = __builtin_amdgcn_mfma_f32_16x16x32_bf16(
                    af[i], bfr[j], acc[i][j], 0, 0, 0);
    }

    // Epilogue: C/D layout col=lane&15, row=(lane>>4)*4+reg (verified).
    const int ecol = lane & 15;
    const int erow = (lane >> 4) * 4;
#pragma unroll
    for (int i = 0; i < 4; ++i)
#pragma unroll
        for (int j = 0; j < 4; ++j)
#pragma unroll
            for (int r = 0; r < 4; ++r) {
                int gi = row0 + wr * 64 + i * 16 + erow + r;
                int gj = col0 + wc * 64 + j * 16 + ecol;
                D[(size_t)gi * Ndim + gj] = (OutT)acc[i][j][r];
            }
}

extern "C" void kernel_launch(void* const* d_in, const int* in_sizes, int n_in,
                              void* d_out, int out_size, void* d_ws, size_t ws_size,
                              hipStream_t stream) {
    const float* x = (const float*)d_in[0];
    float* out = (float*)d_out;

    const int MN = 2048;
    const size_t mat = (size_t)MN * MN;  // 4M elems
    const size_t bmat = 4 * mat;         // 16M elems (B=4)

    // Workspace layout (80 MiB total):
    __bf16* Cb = (__bf16*)d_ws;   //  8 MiB
    __bf16* Sb = Cb + mat;        //  8 MiB
    __bf16* xb = Sb + mat;        // 32 MiB
    __bf16* tT = xb + bmat;       // 32 MiB

    basis_kernel<<<mat / 256, 256, 0, stream>>>(Cb, Sb);
    cvt_kernel<<<bmat / 4 / 256, 256, 0, stream>>>((const float4*)x, (bf16x4*)xb);

    dim3 grid(MN / BN, MN / BM, 4);  // (8, 16, 4) = 512 blocks, 2/CU
    // pass1: tT[b][v][p] = sum_q C[v][q] * xb[b][p][q]
    gemm_nt<__bf16><<<grid, 512, 0, stream>>>(Cb, xb, tT, MN, MN,
                                              0L, (long)mat, (long)mat);
    // pass2: out[b][u][v] = sum_p S[u][p] * tT[b][v][p]
    gemm_nt<float><<<grid, 512, 0, stream>>>(Sb, tT, out, MN, MN,
                                             0L, (long)mat, (long)mat);
}